// Round 11
// baseline (6282.803 us; speedup 1.0000x reference)
//
#include <hip/hip_runtime.h>
#include <hip/hip_bf16.h>

#define B   64
#define H   512
#define V   32000
#define T   38
#define G4  2048      // 4*H
#define NSTEP 37      // T-1
#define VT  64        // v-tile per f32-fallback logits block
#define KC  64        // k-chunk (fallback)
#define LDP 68        // LDS pad (fallback)
#define NTILE 250     // V/128 logits tiles
#define DELTA 0.008f  // >= 2*eps_mfma (1-term bf16 err ~1e-3; R7-validated)
#define VCAP 512      // per-block candidate list capacity (expected ~74)

typedef __attribute__((ext_vector_type(8))) short short8;
typedef __attribute__((ext_vector_type(4))) float f32x4;
typedef unsigned long long ull;

__device__ __forceinline__ float sigf(float x){ return 1.0f/(1.0f + expf(-x)); }

__device__ __forceinline__ unsigned int fkey(float x){
  unsigned int u = __float_as_uint(x);
  return (u & 0x80000000u) ? ~u : (u | 0x80000000u);
}
__device__ __forceinline__ float fromkey(unsigned int k){
  unsigned int u = (k & 0x80000000u) ? (k & 0x7fffffffu) : ~k;
  return __uint_as_float(u);
}
__device__ __forceinline__ ull mkkey(float v, int idx){
  return ((ull)fkey(v)<<32) | (ull)(unsigned int)(~(unsigned int)idx);
}
__device__ __forceinline__ unsigned short f2bf(float x){  // RNE
  unsigned int u = __float_as_uint(x);
  unsigned int r = (u + 0x7FFFu + ((u >> 16) & 1u)) >> 16;
  return (unsigned short)r;
}
__device__ __forceinline__ float bf2f(unsigned short u){
  return __uint_as_float((unsigned int)u << 16);
}

// ---------------- init: h/c parity0 = feat^T per layer; argmax slots = 0
__global__ __launch_bounds__(256) void k_init_state(const float* __restrict__ feat,
                                                    float* __restrict__ hT, float* __restrict__ cT,
                                                    ull* __restrict__ packed){
  int idx = blockIdx.x*blockDim.x + threadIdx.x;     // covers 3*H*B = 98304
  if (idx < 3*H*B){
    int b = idx & (B-1);
    int k = (idx >> 6) & (H-1);
    float v = feat[(size_t)b*H + k];
    hT[idx] = v;
    cT[idx] = v;
  }
  if (idx < NSTEP*B) packed[idx] = 0ULL;
}

// ---------------- W_proj f32 -> bf16 (hi only; rescore uses exact f32)
__global__ __launch_bounds__(256) void k_convW(const float* __restrict__ src,
                                               unsigned short* __restrict__ hi){
  int i = blockIdx.x*blockDim.x + threadIdx.x;     // per 4 elems
  float4 f = ((const float4*)src)[i];
  ushort4 h4 = make_ushort4(f2bf(f.x), f2bf(f.y), f2bf(f.z), f2bf(f.w));
  ((ushort4*)hi)[i] = h4;
}

// ---------------- gfeat[gate][j][b] = feat[b] . W_ih0[gate*H+j][0:H] + biases
__global__ __launch_bounds__(256) void k_gfeat(const float* __restrict__ feat,
                                               const float* __restrict__ Wih0,
                                               const float* __restrict__ b_ih,
                                               const float* __restrict__ b_hh,
                                               float* __restrict__ gfeatT){
  int j = blockIdx.x;
  int b = threadIdx.x;
  int gate = threadIdx.y;
  int r = gate*H + j;
  const float* w = Wih0 + (size_t)r*(2*H);
  const float* x = feat + (size_t)b*H;
  float acc = 0.f;
  #pragma unroll 4
  for (int k=0;k<H;k++) acc = fmaf(w[k], x[k], acc);
  gfeatT[((size_t)gate*H + j)*B + b] = acc + b_ih[r] + b_hh[r];
}

// ---------------- output column 0
__global__ __launch_bounds__(256) void k_row0(const float* __restrict__ embed_,
                                              const float* __restrict__ Wp,
                                              const float* __restrict__ bp,
                                              unsigned short* __restrict__ dstBf,  // staged bf16 [b][v]
                                              float* __restrict__ dstF, int mode){ // direct f32 [b][v][t=0]
  int v = blockIdx.x*blockDim.x + threadIdx.x;
  if (v >= V) return;
  const float4* e = (const float4*)embed_;                 // row 0 = SOS
  const float4* w = (const float4*)(Wp + (size_t)v*H);
  float acc = 0.f;
  #pragma unroll 4
  for (int k=0;k<H/4;k++){
    float4 a = e[k], c = w[k];
    acc += a.x*c.x + a.y*c.y + a.z*c.z + a.w*c.w;
  }
  acc += bp[v];
  if (mode == 0){
    unsigned short bv = f2bf(acc);
    for (int b=0;b<B;b++) __builtin_nontemporal_store(bv, dstBf + (size_t)b*V + v);
  } else {
    for (int b=0;b<B;b++) dstF[((size_t)b*V + v)*T] = acc;
  }
}

// ---------------- one LSTM layer for one step (R7-proven: 4 waves, scalar streams)
__global__ __launch_bounds__(256) void k_lstm(int layer, int s,
    const float* __restrict__ Wih, const float* __restrict__ Whh,
    const float* __restrict__ bias_ih, const float* __restrict__ bias_hh,
    const float* __restrict__ gfeatT,
    const float* __restrict__ embed_,
    const ull* __restrict__ packedPrev,
    const float* __restrict__ xLowerT,
    const float* __restrict__ hOldT,
    float* __restrict__ hNewT,
    float* __restrict__ cT_,
    unsigned short* __restrict__ hBf,      // optional: [B][H] bf16 hi plane
    float* __restrict__ hF)                // optional: [B][H] f32 copy of new h
{
  const int j  = blockIdx.x;
  const int b  = threadIdx.x;
  const int ks = threadIdx.y;
  __shared__ float part[4][4][B];

  const int kbase = (ks & 1)*256;
  const float *w0,*w1,*w2,*w3;
  const float* xptr = nullptr;
  const float* eptr = nullptr;

  if (ks < 2){
    if (layer == 0){
      const size_t gs = (size_t)H*(2*H);
      w0 = Wih + (size_t)j*(2*H) + H + kbase;
      w1 = w0 + gs; w2 = w0 + 2*gs; w3 = w0 + 3*gs;
      int er = 0;
      if (s > 0) er = (int)(~(unsigned int)(packedPrev[b] & 0xFFFFFFFFull));
      eptr = embed_ + (size_t)er*H + kbase;
    } else {
      const size_t gs = (size_t)H*H;
      w0 = Wih + (size_t)j*H + kbase;
      w1 = w0 + gs; w2 = w0 + 2*gs; w3 = w0 + 3*gs;
      xptr = xLowerT + (size_t)kbase*B + b;
    }
  } else {
    const size_t gs = (size_t)H*H;
    w0 = Whh + (size_t)j*H + kbase;
    w1 = w0 + gs; w2 = w0 + 2*gs; w3 = w0 + 3*gs;
    xptr = hOldT + (size_t)kbase*B + b;
  }

  float a0=0.f, a1=0.f, a2=0.f, a3=0.f;
  if (eptr){
    #pragma unroll 4
    for (int k=0;k<256;k++){
      float xv = eptr[k];
      a0 = fmaf(w0[k], xv, a0); a1 = fmaf(w1[k], xv, a1);
      a2 = fmaf(w2[k], xv, a2); a3 = fmaf(w3[k], xv, a3);
    }
  } else {
    #pragma unroll 4
    for (int k=0;k<256;k++){
      float xv = xptr[(size_t)k*B];
      a0 = fmaf(w0[k], xv, a0); a1 = fmaf(w1[k], xv, a1);
      a2 = fmaf(w2[k], xv, a2); a3 = fmaf(w3[k], xv, a3);
    }
  }
  part[ks][0][b]=a0; part[ks][1][b]=a1; part[ks][2][b]=a2; part[ks][3][b]=a3;
  __syncthreads();

  if (ks == 0){
    float g[4];
    #pragma unroll
    for (int gt=0; gt<4; gt++){
      float sum = part[0][gt][b] + part[1][gt][b] + part[2][gt][b] + part[3][gt][b];
      if (layer == 0) sum += gfeatT[((size_t)gt*H + j)*B + b];
      else            sum += bias_ih[gt*H + j] + bias_hh[gt*H + j];
      g[gt] = sum;
    }
    float i_ = sigf(g[0]);
    float f_ = sigf(g[1]);
    float gg = tanhf(g[2]);
    float o_ = sigf(g[3]);
    float cold = cT_[(size_t)j*B + b];
    float c2 = f_*cold + i_*gg;
    float h2 = o_*tanhf(c2);
    cT_[(size_t)j*B + b]  = c2;
    hNewT[(size_t)j*B + b] = h2;
    if (hBf) hBf[(size_t)b*H + j] = f2bf(h2);
    if (hF)  hF [(size_t)b*H + j] = h2;
  }
}

// ---------------- 1-term bf16 MFMA logits + per-block-local exact-f32 rescore
// D tile: col(v)=lane&15, row(b)=(lane>>4)*4+reg (verified R2 on-harness).
// Rescore correctness: true winner v* in block T has L_mfma(v*) >= gmax-DELTA
// >= M_T-DELTA, so the per-b local threshold captures it; atomicMax with exact
// f32 keys over all blocks yields the exact argmax. No cross-block reads.
__global__ __launch_bounds__(256) void k_logits_mfma(
    const unsigned short* __restrict__ Wbf,   // [V][H] bf16
    const unsigned short* __restrict__ h2bf,  // [B][H] bf16 (hi)
    const float* __restrict__ bp,
    unsigned short* __restrict__ dst,         // [B][V] bf16 plane
    const float* __restrict__ hF,             // [B][H] f32 (prev kernel, coherent)
    const float* __restrict__ WpF,            // f32 W_proj (input, coherent)
    ull* __restrict__ packedS)                // argmax out for this step
{
  const int tid  = threadIdx.x;
  const int wave = tid >> 6;
  const int lane = tid & 63;
  const int col  = lane & 15;
  const int grp  = lane >> 4;
  const int v0   = blockIdx.x*128 + wave*32;

  f32x4 acc[4][2] = {{{0.f,0.f,0.f,0.f},{0.f,0.f,0.f,0.f}},
                     {{0.f,0.f,0.f,0.f},{0.f,0.f,0.f,0.f}},
                     {{0.f,0.f,0.f,0.f},{0.f,0.f,0.f,0.f}},
                     {{0.f,0.f,0.f,0.f},{0.f,0.f,0.f,0.f}}};

  const unsigned short* hp = h2bf + (size_t)col*H + grp*8;
  const unsigned short* wp = Wbf  + (size_t)(v0+col)*H + grp*8;

  for (int k0 = 0; k0 < H; k0 += 32){
    short8 afr[4], bfr[2];
    #pragma unroll
    for (int bt=0;bt<4;bt++)
      afr[bt] = *(const short8*)(hp + (size_t)bt*16*H + k0);
    #pragma unroll
    for (int vt=0;vt<2;vt++)
      bfr[vt] = *(const short8*)(wp + (size_t)vt*16*H + k0);
    #pragma unroll
    for (int bt=0;bt<4;bt++)
      #pragma unroll
      for (int vt=0;vt<2;vt++)
        acc[bt][vt] = __builtin_amdgcn_mfma_f32_16x16x32_bf16(afr[bt], bfr[vt], acc[bt][vt], 0,0,0);
  }

  float bias0 = bp[v0 + col];
  float bias1 = bp[v0 + 16 + col];

  ull keys[4][4];
  #pragma unroll
  for (int bt=0;bt<4;bt++){
    #pragma unroll
    for (int r=0;r<4;r++){
      int b = bt*16 + grp*4 + r;
      float val0 = acc[bt][0][r] + bias0;
      float val1 = acc[bt][1][r] + bias1;
      __builtin_nontemporal_store(f2bf(val0), dst + (size_t)b*V + v0 + col);
      __builtin_nontemporal_store(f2bf(val1), dst + (size_t)b*V + v0 + 16 + col);
      float m; int mv;
      if (val1 > val0){ m = val1; mv = v0+16+col; } else { m = val0; mv = v0+col; }
      keys[bt][r] = mkkey(m, mv);
    }
  }
  // per-b max over this block's 128 v's: 16-col shuffle reduce, then cross-wave
  #pragma unroll
  for (int bt=0;bt<4;bt++)
    #pragma unroll
    for (int r=0;r<4;r++){
      ull k2 = keys[bt][r];
      #pragma unroll
      for (int m=1;m<16;m<<=1){
        ull o = __shfl_xor(k2, m, 64);
        if (o > k2) k2 = o;
      }
      keys[bt][r] = k2;
    }

  __shared__ ull wred[4][64];
  __shared__ float bthr[B];
  __shared__ int  vlist[VCAP];
  __shared__ int  vcount;
  if (tid == 0) vcount = 0;
  if (col == 0){
    #pragma unroll
    for (int bt=0;bt<4;bt++)
      #pragma unroll
      for (int r=0;r<4;r++)
        wred[wave][bt*16 + grp*4 + r] = keys[bt][r];
  }
  __syncthreads();
  if (tid < 64){
    ull best = wred[0][tid];
    #pragma unroll
    for (int w=1;w<4;w++) if (wred[w][tid] > best) best = wred[w][tid];
    bthr[tid] = fromkey((unsigned int)(best >> 32)) - DELTA;   // local threshold
  }
  __syncthreads();

  // candidate collection: each thread re-checks its 32 values against bthr[b]
  #pragma unroll
  for (int bt=0;bt<4;bt++){
    #pragma unroll
    for (int r=0;r<4;r++){
      int b = bt*16 + grp*4 + r;
      float thr = bthr[b];
      float val0 = acc[bt][0][r] + bias0;
      float val1 = acc[bt][1][r] + bias1;
      #pragma unroll
      for (int vt=0; vt<2; vt++){
        float val = vt ? val1 : val0;
        int v = v0 + vt*16 + col;
        if (val >= thr){
          int i = atomicAdd(&vcount, 1);
          if (i < VCAP) vlist[i] = (b << 15) | v;
          else {  // ultra-rare overflow: exact serial rescore inline
            const float* wrow = WpF + (size_t)v*H;
            const float* hrow = hF  + (size_t)b*H;
            float a = 0.f;
            for (int k=0;k<H;k++) a = fmaf(wrow[k], hrow[k], a);
            atomicMax(packedS + b, mkkey(a + bp[v], v));
          }
        }
      }
    }
  }
  __syncthreads();
  const int nc = min(vcount, VCAP);

  // exact f32 rescore: one wave per candidate, atomicMax exact key
  for (int i = wave; i < nc; i += 4){
    int pk = vlist[i];
    int b  = pk >> 15;
    int v  = pk & 0x7FFF;
    const float* wrow = WpF + (size_t)v*H;
    const float* hrow = hF  + (size_t)b*H;
    float a = 0.f;
    #pragma unroll
    for (int k=lane; k<H; k+=64) a = fmaf(wrow[k], hrow[k], a);
    #pragma unroll
    for (int m=32; m>0; m>>=1) a += __shfl_xor(a, m, 64);
    if (lane == 0) atomicMax(packedS + b, mkkey(a + bp[v], v));
  }
}

// ---------------- f32 fallback logits (no-workspace path, direct strided out)
__global__ __launch_bounds__(256) void k_logits(
    const float* __restrict__ h2T,
    const float* __restrict__ Wp,
    const float* __restrict__ bp,
    float* __restrict__ dst, int strideV, int strideB,
    ull* __restrict__ packedS)
{
  __shared__ float Wt[KC][LDP];
  __shared__ float Xt[KC][LDP];
  __shared__ ull red[B][17];

  const int tid = threadIdx.x;
  const int v0  = blockIdx.x * VT;
  const int tv  = tid & 15;
  const int tb  = tid >> 4;
  const int vr  = tid >> 2;
  const int kq  = tid & 3;

  float acc[4][4];
  #pragma unroll
  for (int i=0;i<4;i++)
    #pragma unroll
    for (int q=0;q<4;q++) acc[i][q] = 0.f;

  for (int k0=0; k0<H; k0+=KC){
    __syncthreads();
    const float* wsrc = Wp + (size_t)(v0+vr)*H + k0 + kq*16;
    #pragma unroll
    for (int i=0;i<4;i++){
      float4 w4 = *(const float4*)(wsrc + i*4);
      int kk = kq*16 + i*4;
      Wt[kk+0][vr]=w4.x; Wt[kk+1][vr]=w4.y; Wt[kk+2][vr]=w4.z; Wt[kk+3][vr]=w4.w;
    }
    const float* xsrc = h2T + (size_t)(k0+vr)*B + kq*16;
    #pragma unroll
    for (int i=0;i<4;i++){
      float4 x4 = *(const float4*)(xsrc + i*4);
      int bb = kq*16 + i*4;
      Xt[vr][bb+0]=x4.x; Xt[vr][bb+1]=x4.y; Xt[vr][bb+2]=x4.z; Xt[vr][bb+3]=x4.w;
    }
    __syncthreads();
    #pragma unroll 8
    for (int k=0;k<KC;k++){
      float4 w4 = *(const float4*)&Wt[k][tv<<2];
      float4 x4 = *(const float4*)&Xt[k][tb<<2];
      acc[0][0]=fmaf(x4.x,w4.x,acc[0][0]); acc[0][1]=fmaf(x4.x,w4.y,acc[0][1]);
      acc[0][2]=fmaf(x4.x,w4.z,acc[0][2]); acc[0][3]=fmaf(x4.x,w4.w,acc[0][3]);
      acc[1][0]=fmaf(x4.y,w4.x,acc[1][0]); acc[1][1]=fmaf(x4.y,w4.y,acc[1][1]);
      acc[1][2]=fmaf(x4.y,w4.z,acc[1][2]); acc[1][3]=fmaf(x4.y,w4.w,acc[1][3]);
      acc[2][0]=fmaf(x4.z,w4.x,acc[2][0]); acc[2][1]=fmaf(x4.z,w4.y,acc[2][1]);
      acc[2][2]=fmaf(x4.z,w4.z,acc[2][2]); acc[2][3]=fmaf(x4.z,w4.w,acc[2][3]);
      acc[3][0]=fmaf(x4.w,w4.x,acc[3][0]); acc[3][1]=fmaf(x4.w,w4.y,acc[3][1]);
      acc[3][2]=fmaf(x4.w,w4.z,acc[3][2]); acc[3][3]=fmaf(x4.w,w4.w,acc[3][3]);
    }
  }

  float4 bb4 = *(const float4*)(bp + v0 + (tv<<2));
  float barr[4] = {bb4.x, bb4.y, bb4.z, bb4.w};
  float vals[4][4];
  #pragma unroll
  for (int bj=0;bj<4;bj++)
    #pragma unroll
    for (int vi=0;vi<4;vi++) vals[bj][vi] = acc[bj][vi] + barr[vi];

  #pragma unroll
  for (int bj=0;bj<4;bj++){
    int b = (tb<<2)+bj;
    #pragma unroll
    for (int vi=0;vi<4;vi++)
      dst[(size_t)b*strideB + (size_t)(v0+(tv<<2)+vi)*strideV] = vals[bj][vi];
  }

  #pragma unroll
  for (int bj=0;bj<4;bj++){
    float m = vals[bj][0]; int mi = v0+(tv<<2);
    #pragma unroll
    for (int vi=1;vi<4;vi++){
      if (vals[bj][vi] > m){ m = vals[bj][vi]; mi = v0+(tv<<2)+vi; }
    }
    red[(tb<<2)+bj][tv] = mkkey(m, mi);
  }
  __syncthreads();
  if (tid < B){
    ull best = red[tid][0];
    #pragma unroll
    for (int t2=1;t2<16;t2++){ ull k2 = red[tid][t2]; if (k2 > best) best = k2; }
    atomicMax(packedS + tid, best);
  }
}

// ---------------- LDS-tiled transpose: stage bf16 [t][b][v] -> out f32 [b][v][t]
__global__ __launch_bounds__(256) void k_transpose(const unsigned short* __restrict__ stage,
                                                   float* __restrict__ out){
  __shared__ float tile[64][40];           // [v-local][t], padded
  const int b  = blockIdx.x / (V/64);
  const int vt = blockIdx.x % (V/64);
  const int v0 = vt*64;
  const int tid = threadIdx.x;

  for (int idx = tid; idx < T*64; idx += 256){
    int t  = idx >> 6;
    int vl = idx & 63;
    unsigned short u = __builtin_nontemporal_load(stage + (size_t)t*B*V + (size_t)b*V + v0 + vl);
    tile[vl][t] = bf2f(u);
  }
  __syncthreads();

  float* obase = out + ((size_t)b*V + v0)*T;
  for (int idx = tid; idx < (T*64)/4; idx += 256){   // 608 16B stores, contiguous
    int e = idx*4;
    f32x4 o;
    o[0] = tile[(e+0)/T][(e+0)%T];
    o[1] = tile[(e+1)/T][(e+1)%T];
    o[2] = tile[(e+2)/T][(e+2)%T];
    o[3] = tile[(e+3)/T][(e+3)%T];
    __builtin_nontemporal_store(o, (f32x4*)(obase + e));
  }
}

extern "C" void kernel_launch(void* const* d_in, const int* in_sizes, int n_in,
                              void* d_out, int out_size, void* d_ws, size_t ws_size,
                              hipStream_t stream){
  const float* feat      = (const float*)d_in[0];
  const float* W_ih0     = (const float*)d_in[1];
  const float* W_hh0     = (const float*)d_in[2];
  const float* W_ih_rest = (const float*)d_in[3];
  const float* W_hh_rest = (const float*)d_in[4];
  const float* b_ih      = (const float*)d_in[5];
  const float* b_hh      = (const float*)d_in[6];
  const float* embed     = (const float*)d_in[7];
  const float* W_proj    = (const float*)d_in[8];
  const float* b_proj    = (const float*)d_in[9];
  // inputs 10..15 (attention weights) are mathematically dead: enc is l-uniform
  // so softmax over l is uniform and ctx == feat at every step.
  float* out = (float*)d_out;

  char* ws = (char*)d_ws;
  size_t off = 0;
  float* hT = (float*)(ws + off); off += (size_t)2*3*H*B*4;
  float* cT = (float*)(ws + off); off += (size_t)3*H*B*4;
  float* gfeatT = (float*)(ws + off); off += (size_t)4*H*B*4;
  ull* packed = (ull*)(ws + off); off += (size_t)NSTEP*B*8;
  unsigned short* h2bf = (unsigned short*)(ws + off); off += (size_t)B*H*2;
  float* hF32 = (float*)(ws + off); off += (size_t)B*H*4;
  off = (off + 255) & ~(size_t)255;
  unsigned short* Whi = (unsigned short*)(ws + off); off += (size_t)V*H*2;
  off = (off + 255) & ~(size_t)255;
  unsigned short* stage = (unsigned short*)(ws + off);
  const size_t need = off + (size_t)T*B*V*2;   // ~190 MB total
  const bool fast = (ws_size >= need);

  dim3 bl64x4(64,4);
  k_init_state<<<(3*H*B + 255)/256, 256, 0, stream>>>(feat, hT, cT, packed);
  k_gfeat<<<H, bl64x4, 0, stream>>>(feat, W_ih0, b_ih, b_hh, gfeatT);
  if (fast){
    k_convW<<<(V*H/4)/256, 256, 0, stream>>>(W_proj, Whi);
    k_row0<<<(V+255)/256, 256, 0, stream>>>(embed, W_proj, b_proj, stage, (float*)nullptr, 0);
  } else {
    k_row0<<<(V+255)/256, 256, 0, stream>>>(embed, W_proj, b_proj, (unsigned short*)nullptr, out, 1);
  }

  const size_t LHB = (size_t)H*B;
  for (int s=0; s<NSTEP; s++){
    const int p = s & 1, q = p ^ 1;
    float* hOld = hT + (size_t)p*3*LHB;
    float* hNew = hT + (size_t)q*3*LHB;
    const ull* pk = packed + (size_t)(s>0 ? s-1 : 0)*B;

    k_lstm<<<H, bl64x4, 0, stream>>>(0, s, W_ih0, W_hh0,
        b_ih, b_hh, gfeatT, embed, pk,
        (const float*)nullptr, hOld + 0*LHB, hNew + 0*LHB, cT + 0*LHB,
        (unsigned short*)nullptr, (float*)nullptr);
    k_lstm<<<H, bl64x4, 0, stream>>>(1, s, W_ih_rest, W_hh_rest,
        b_ih + 1*G4, b_hh + 1*G4, (const float*)nullptr, (const float*)nullptr,
        (const ull*)nullptr,
        hNew + 0*LHB, hOld + 1*LHB, hNew + 1*LHB, cT + 1*LHB,
        (unsigned short*)nullptr, (float*)nullptr);
    k_lstm<<<H, bl64x4, 0, stream>>>(2, s, W_ih_rest + (size_t)G4*H, W_hh_rest + (size_t)G4*H,
        b_ih + 2*G4, b_hh + 2*G4, (const float*)nullptr, (const float*)nullptr,
        (const ull*)nullptr,
        hNew + 1*LHB, hOld + 2*LHB, hNew + 2*LHB, cT + 2*LHB,
        fast ? h2bf : (unsigned short*)nullptr,
        fast ? hF32 : (float*)nullptr);

    if (fast){
      unsigned short* plane = stage + (size_t)(s+1)*B*V;
      k_logits_mfma<<<NTILE, 256, 0, stream>>>(Whi, h2bf, b_proj, plane,
                                               hF32, W_proj, packed + (size_t)s*B);
    } else {
      k_logits<<<V/VT, 256, 0, stream>>>(hNew + 2*LHB, W_proj, b_proj,
          out + (s+1), T, V*T, packed + (size_t)s*B);
    }
  }

  if (fast) k_transpose<<<B*(V/64), 256, 0, stream>>>(stage, out);
}

// Round 12
// 3890.706 us; speedup vs baseline: 1.6148x; 1.6148x over previous
//
#include <hip/hip_runtime.h>
#include <hip/hip_bf16.h>

#define B   64
#define H   512
#define V   32000
#define T   38
#define G4  2048      // 4*H
#define NSTEP 37      // T-1
#define VT  64        // v-tile per f32-fallback logits block
#define KC  64        // k-chunk (fallback)
#define LDP 68        // LDS pad (fallback)
#define NTILE 250     // V/128 logits tiles
#define DELTA 0.008f  // >= 2*(mfma 1-term err ~1e-3 + bf16 storage quantum ~2e-3)
#define MAXC 128      // max exact-rescore candidates per row

typedef __attribute__((ext_vector_type(8))) short short8;
typedef __attribute__((ext_vector_type(4))) float f32x4;
typedef unsigned long long ull;

__device__ __forceinline__ float sigf(float x){ return 1.0f/(1.0f + expf(-x)); }

__device__ __forceinline__ unsigned int fkey(float x){
  unsigned int u = __float_as_uint(x);
  return (u & 0x80000000u) ? ~u : (u | 0x80000000u);
}
__device__ __forceinline__ float fromkey(unsigned int k){
  unsigned int u = (k & 0x80000000u) ? (k & 0x7fffffffu) : ~k;
  return __uint_as_float(u);
}
__device__ __forceinline__ ull mkkey(float v, int idx){
  return ((ull)fkey(v)<<32) | (ull)(unsigned int)(~(unsigned int)idx);
}
__device__ __forceinline__ unsigned short f2bf(float x){  // RNE
  unsigned int u = __float_as_uint(x);
  unsigned int r = (u + 0x7FFFu + ((u >> 16) & 1u)) >> 16;
  return (unsigned short)r;
}
__device__ __forceinline__ float bf2f(unsigned short u){
  return __uint_as_float((unsigned int)u << 16);
}

// ---------------- init: h/c parity0 = feat^T per layer; argmax slots = 0
__global__ __launch_bounds__(256) void k_init_state(const float* __restrict__ feat,
                                                    float* __restrict__ hT, float* __restrict__ cT,
                                                    ull* __restrict__ packed){
  int idx = blockIdx.x*blockDim.x + threadIdx.x;     // covers 3*H*B = 98304
  if (idx < 3*H*B){
    int b = idx & (B-1);
    int k = (idx >> 6) & (H-1);
    float v = feat[(size_t)b*H + k];
    hT[idx] = v;
    cT[idx] = v;
  }
  if (idx < NSTEP*B) packed[idx] = 0ULL;
}

// ---------------- W_proj f32 -> bf16 (hi only; rescue re-scores in exact f32)
__global__ __launch_bounds__(256) void k_convW(const float* __restrict__ src,
                                               unsigned short* __restrict__ hi){
  int i = blockIdx.x*blockDim.x + threadIdx.x;     // per 4 elems
  float4 f = ((const float4*)src)[i];
  ushort4 h4 = make_ushort4(f2bf(f.x), f2bf(f.y), f2bf(f.z), f2bf(f.w));
  ((ushort4*)hi)[i] = h4;
}

// ---------------- gfeat[gate][j][b] = feat[b] . W_ih0[gate*H+j][0:H] + biases
__global__ __launch_bounds__(256) void k_gfeat(const float* __restrict__ feat,
                                               const float* __restrict__ Wih0,
                                               const float* __restrict__ b_ih,
                                               const float* __restrict__ b_hh,
                                               float* __restrict__ gfeatT){
  int j = blockIdx.x;
  int b = threadIdx.x;
  int gate = threadIdx.y;
  int r = gate*H + j;
  const float* w = Wih0 + (size_t)r*(2*H);
  const float* x = feat + (size_t)b*H;
  float acc = 0.f;
  #pragma unroll 4
  for (int k=0;k<H;k++) acc = fmaf(w[k], x[k], acc);
  gfeatT[((size_t)gate*H + j)*B + b] = acc + b_ih[r] + b_hh[r];
}

// ---------------- output column 0
__global__ __launch_bounds__(256) void k_row0(const float* __restrict__ embed_,
                                              const float* __restrict__ Wp,
                                              const float* __restrict__ bp,
                                              unsigned short* __restrict__ dstBf,  // staged bf16 [b][v]
                                              float* __restrict__ dstF, int mode){ // direct f32 [b][v][t=0]
  int v = blockIdx.x*blockDim.x + threadIdx.x;
  if (v >= V) return;
  const float4* e = (const float4*)embed_;                 // row 0 = SOS
  const float4* w = (const float4*)(Wp + (size_t)v*H);
  float acc = 0.f;
  #pragma unroll 4
  for (int k=0;k<H/4;k++){
    float4 a = e[k], c = w[k];
    acc += a.x*c.x + a.y*c.y + a.z*c.z + a.w*c.w;
  }
  acc += bp[v];
  if (mode == 0){
    unsigned short bv = f2bf(acc);
    for (int b=0;b<B;b++) __builtin_nontemporal_store(bv, dstBf + (size_t)b*V + v);
  } else {
    for (int b=0;b<B;b++) dstF[((size_t)b*V + v)*T] = acc;
  }
}

// ---------------- one LSTM layer for one step
__global__ __launch_bounds__(256) void k_lstm(int layer, int s,
    const float* __restrict__ Wih, const float* __restrict__ Whh,
    const float* __restrict__ bias_ih, const float* __restrict__ bias_hh,
    const float* __restrict__ gfeatT,
    const float* __restrict__ embed_,
    const ull* __restrict__ packedPrev,
    const float* __restrict__ xLowerT,
    const float* __restrict__ hOldT,
    float* __restrict__ hNewT,
    float* __restrict__ cT_,
    unsigned short* __restrict__ hBf,      // optional: [B][H] bf16 hi plane
    float* __restrict__ hF)                // optional: [B][H] f32 copy of new h
{
  const int j  = blockIdx.x;
  const int b  = threadIdx.x;
  const int ks = threadIdx.y;
  __shared__ float part[4][4][B];

  const int kbase = (ks & 1)*256;
  const float *w0,*w1,*w2,*w3;
  const float* xptr = nullptr;
  const float* eptr = nullptr;

  if (ks < 2){
    if (layer == 0){
      const size_t gs = (size_t)H*(2*H);
      w0 = Wih + (size_t)j*(2*H) + H + kbase;
      w1 = w0 + gs; w2 = w0 + 2*gs; w3 = w0 + 3*gs;
      int er = 0;
      if (s > 0) er = (int)(~(unsigned int)(packedPrev[b] & 0xFFFFFFFFull));
      eptr = embed_ + (size_t)er*H + kbase;
    } else {
      const size_t gs = (size_t)H*H;
      w0 = Wih + (size_t)j*H + kbase;
      w1 = w0 + gs; w2 = w0 + 2*gs; w3 = w0 + 3*gs;
      xptr = xLowerT + (size_t)kbase*B + b;
    }
  } else {
    const size_t gs = (size_t)H*H;
    w0 = Whh + (size_t)j*H + kbase;
    w1 = w0 + gs; w2 = w0 + 2*gs; w3 = w0 + 3*gs;
    xptr = hOldT + (size_t)kbase*B + b;
  }

  float a0=0.f, a1=0.f, a2=0.f, a3=0.f;
  if (eptr){
    #pragma unroll 4
    for (int k=0;k<256;k++){
      float xv = eptr[k];
      a0 = fmaf(w0[k], xv, a0); a1 = fmaf(w1[k], xv, a1);
      a2 = fmaf(w2[k], xv, a2); a3 = fmaf(w3[k], xv, a3);
    }
  } else {
    #pragma unroll 4
    for (int k=0;k<256;k++){
      float xv = xptr[(size_t)k*B];
      a0 = fmaf(w0[k], xv, a0); a1 = fmaf(w1[k], xv, a1);
      a2 = fmaf(w2[k], xv, a2); a3 = fmaf(w3[k], xv, a3);
    }
  }
  part[ks][0][b]=a0; part[ks][1][b]=a1; part[ks][2][b]=a2; part[ks][3][b]=a3;
  __syncthreads();

  if (ks == 0){
    float g[4];
    #pragma unroll
    for (int gt=0; gt<4; gt++){
      float sum = part[0][gt][b] + part[1][gt][b] + part[2][gt][b] + part[3][gt][b];
      if (layer == 0) sum += gfeatT[((size_t)gt*H + j)*B + b];
      else            sum += bias_ih[gt*H + j] + bias_hh[gt*H + j];
      g[gt] = sum;
    }
    float i_ = sigf(g[0]);
    float f_ = sigf(g[1]);
    float gg = tanhf(g[2]);
    float o_ = sigf(g[3]);
    float cold = cT_[(size_t)j*B + b];
    float c2 = f_*cold + i_*gg;
    float h2 = o_*tanhf(c2);
    cT_[(size_t)j*B + b]  = c2;
    hNewT[(size_t)j*B + b] = h2;
    if (hBf) hBf[(size_t)b*H + j] = f2bf(h2);
    if (hF)  hF [(size_t)b*H + j] = h2;
  }
}

// ---------------- 1-term bf16 MFMA logits -> bf16 plane (nt) + tilemax [B][NTILE]
// D tile: col(v)=lane&15, row(b)=(lane>>4)*4+reg (verified R2 on-harness).
__global__ __launch_bounds__(256) void k_logits_mfma(
    const unsigned short* __restrict__ Wbf,   // [V][H] bf16
    const unsigned short* __restrict__ h2bf,  // [B][H] bf16 (hi)
    const float* __restrict__ bp,
    unsigned short* __restrict__ dst,         // [B][V] bf16 plane
    ull* __restrict__ tilemax)                // [B][NTILE]
{
  const int tid  = threadIdx.x;
  const int wave = tid >> 6;
  const int lane = tid & 63;
  const int col  = lane & 15;
  const int grp  = lane >> 4;
  const int v0   = blockIdx.x*128 + wave*32;

  f32x4 acc[4][2] = {{{0.f,0.f,0.f,0.f},{0.f,0.f,0.f,0.f}},
                     {{0.f,0.f,0.f,0.f},{0.f,0.f,0.f,0.f}},
                     {{0.f,0.f,0.f,0.f},{0.f,0.f,0.f,0.f}},
                     {{0.f,0.f,0.f,0.f},{0.f,0.f,0.f,0.f}}};

  const unsigned short* hp = h2bf + (size_t)col*H + grp*8;
  const unsigned short* wp = Wbf  + (size_t)(v0+col)*H + grp*8;

  for (int k0 = 0; k0 < H; k0 += 32){
    short8 afr[4], bfr[2];
    #pragma unroll
    for (int bt=0;bt<4;bt++)
      afr[bt] = *(const short8*)(hp + (size_t)bt*16*H + k0);
    #pragma unroll
    for (int vt=0;vt<2;vt++)
      bfr[vt] = *(const short8*)(wp + (size_t)vt*16*H + k0);
    #pragma unroll
    for (int bt=0;bt<4;bt++)
      #pragma unroll
      for (int vt=0;vt<2;vt++)
        acc[bt][vt] = __builtin_amdgcn_mfma_f32_16x16x32_bf16(afr[bt], bfr[vt], acc[bt][vt], 0,0,0);
  }

  float bias0 = bp[v0 + col];
  float bias1 = bp[v0 + 16 + col];

  ull keys[4][4];
  #pragma unroll
  for (int bt=0;bt<4;bt++){
    #pragma unroll
    for (int r=0;r<4;r++){
      int b = bt*16 + grp*4 + r;
      float val0 = acc[bt][0][r] + bias0;
      float val1 = acc[bt][1][r] + bias1;
      __builtin_nontemporal_store(f2bf(val0), dst + (size_t)b*V + v0 + col);
      __builtin_nontemporal_store(f2bf(val1), dst + (size_t)b*V + v0 + 16 + col);
      float m; int mv;
      if (val1 > val0){ m = val1; mv = v0+16+col; } else { m = val0; mv = v0+col; }
      keys[bt][r] = mkkey(m, mv);
    }
  }
  // reduce over the 16 cols sharing this grp (f32-accurate keys)
  #pragma unroll
  for (int bt=0;bt<4;bt++)
    #pragma unroll
    for (int r=0;r<4;r++){
      ull k2 = keys[bt][r];
      #pragma unroll
      for (int m=1;m<16;m<<=1){
        ull o = __shfl_xor(k2, m, 64);
        if (o > k2) k2 = o;
      }
      keys[bt][r] = k2;
    }

  __shared__ ull wred[4][64];
  if (col == 0){
    #pragma unroll
    for (int bt=0;bt<4;bt++)
      #pragma unroll
      for (int r=0;r<4;r++)
        wred[wave][bt*16 + grp*4 + r] = keys[bt][r];
  }
  __syncthreads();
  if (tid < 64){
    ull best = wred[0][tid];
    #pragma unroll
    for (int w=1;w<4;w++) if (wred[w][tid] > best) best = wred[w][tid];
    tilemax[(size_t)tid*NTILE + blockIdx.x] = best;   // [B][NTILE]: rescue-contiguous
  }
}

// ---------------- rescue: tiny-DELTA tile-directed exact-f32 argmax (one block per b)
__global__ __launch_bounds__(256) void k_rescue(
    const unsigned short* __restrict__ plane,  // bf16 [B][V] plane just written
    const ull* __restrict__ tilemax,           // [B][NTILE], f32-accurate keys
    const float* __restrict__ hF,              // [B][H] f32 (layer2 new h)
    const float* __restrict__ Wp,              // f32 [V][H] original
    const float* __restrict__ bp,
    ull* __restrict__ packedS)
{
  const int b    = blockIdx.x;
  const int tid  = threadIdx.x;
  const int lane = tid & 63;
  const int wave = tid >> 6;

  __shared__ float hrow[H];
  __shared__ ull   keybuf[256];
  __shared__ int   tlist[NTILE];
  __shared__ int   vlist[MAXC];
  __shared__ ull   ckey[MAXC];
  __shared__ int   tcount, vcount;

  for (int k=tid; k<H; k+=256) hrow[k] = hF[(size_t)b*H + k];
  ull myk = (tid < NTILE) ? tilemax[(size_t)b*NTILE + tid] : 0ULL;
  keybuf[tid] = myk;
  if (tid == 0){ tcount = 0; vcount = 0; }
  __syncthreads();
  #pragma unroll
  for (int st=128; st>0; st>>=1){
    if (tid < st){ ull o = keybuf[tid+st]; if (o > keybuf[tid]) keybuf[tid] = o; }
    __syncthreads();
  }
  const float gmax   = fromkey((unsigned int)(keybuf[0] >> 32));
  const float thresh = gmax - DELTA;

  if (tid < NTILE && fromkey((unsigned int)(myk >> 32)) >= thresh){
    int i = atomicAdd(&tcount, 1); tlist[i] = tid;
  }
  __syncthreads();

  const int nt = tcount;
  for (int ti=0; ti<nt; ti++){
    if (tid < 128){
      int v = tlist[ti]*128 + tid;
      float val = bf2f(plane[(size_t)b*V + v]);
      if (val >= thresh){
        int i = atomicAdd(&vcount, 1);
        if (i < MAXC) vlist[i] = v;
      }
    }
  }
  __syncthreads();
  const int nc = min(vcount, MAXC);

  for (int base=0; base<nc; base+=4){
    int i = base + wave;
    if (i < nc){
      int v = vlist[i];
      const float* wrow = Wp + (size_t)v*H;
      float acc = 0.f;
      #pragma unroll
      for (int k=lane; k<H; k+=64) acc = fmaf(wrow[k], hrow[k], acc);
      #pragma unroll
      for (int m=32; m>0; m>>=1) acc += __shfl_xor(acc, m, 64);
      if (lane == 0) ckey[i] = mkkey(acc + bp[v], v);
    }
  }
  __syncthreads();
  if (tid == 0){
    ull best = 0ULL;
    for (int i=0;i<nc;i++) if (ckey[i] > best) best = ckey[i];
    packedS[b] = best;
  }
}

// ---------------- f32 fallback logits (no-workspace path, direct strided out)
__global__ __launch_bounds__(256) void k_logits(
    const float* __restrict__ h2T,
    const float* __restrict__ Wp,
    const float* __restrict__ bp,
    float* __restrict__ dst, int strideV, int strideB,
    ull* __restrict__ packedS)
{
  __shared__ float Wt[KC][LDP];
  __shared__ float Xt[KC][LDP];
  __shared__ ull red[B][17];

  const int tid = threadIdx.x;
  const int v0  = blockIdx.x * VT;
  const int tv  = tid & 15;
  const int tb  = tid >> 4;
  const int vr  = tid >> 2;
  const int kq  = tid & 3;

  float acc[4][4];
  #pragma unroll
  for (int i=0;i<4;i++)
    #pragma unroll
    for (int q=0;q<4;q++) acc[i][q] = 0.f;

  for (int k0=0; k0<H; k0+=KC){
    __syncthreads();
    const float* wsrc = Wp + (size_t)(v0+vr)*H + k0 + kq*16;
    #pragma unroll
    for (int i=0;i<4;i++){
      float4 w4 = *(const float4*)(wsrc + i*4);
      int kk = kq*16 + i*4;
      Wt[kk+0][vr]=w4.x; Wt[kk+1][vr]=w4.y; Wt[kk+2][vr]=w4.z; Wt[kk+3][vr]=w4.w;
    }
    const float* xsrc = h2T + (size_t)(k0+vr)*B + kq*16;
    #pragma unroll
    for (int i=0;i<4;i++){
      float4 x4 = *(const float4*)(xsrc + i*4);
      int bb = kq*16 + i*4;
      Xt[vr][bb+0]=x4.x; Xt[vr][bb+1]=x4.y; Xt[vr][bb+2]=x4.z; Xt[vr][bb+3]=x4.w;
    }
    __syncthreads();
    #pragma unroll 8
    for (int k=0;k<KC;k++){
      float4 w4 = *(const float4*)&Wt[k][tv<<2];
      float4 x4 = *(const float4*)&Xt[k][tb<<2];
      acc[0][0]=fmaf(x4.x,w4.x,acc[0][0]); acc[0][1]=fmaf(x4.x,w4.y,acc[0][1]);
      acc[0][2]=fmaf(x4.x,w4.z,acc[0][2]); acc[0][3]=fmaf(x4.x,w4.w,acc[0][3]);
      acc[1][0]=fmaf(x4.y,w4.x,acc[1][0]); acc[1][1]=fmaf(x4.y,w4.y,acc[1][1]);
      acc[1][2]=fmaf(x4.y,w4.z,acc[1][2]); acc[1][3]=fmaf(x4.y,w4.w,acc[1][3]);
      acc[2][0]=fmaf(x4.z,w4.x,acc[2][0]); acc[2][1]=fmaf(x4.z,w4.y,acc[2][1]);
      acc[2][2]=fmaf(x4.z,w4.z,acc[2][2]); acc[2][3]=fmaf(x4.z,w4.w,acc[2][3]);
      acc[3][0]=fmaf(x4.w,w4.x,acc[3][0]); acc[3][1]=fmaf(x4.w,w4.y,acc[3][1]);
      acc[3][2]=fmaf(x4.w,w4.z,acc[3][2]); acc[3][3]=fmaf(x4.w,w4.w,acc[3][3]);
    }
  }

  float4 bb4 = *(const float4*)(bp + v0 + (tv<<2));
  float barr[4] = {bb4.x, bb4.y, bb4.z, bb4.w};
  float vals[4][4];
  #pragma unroll
  for (int bj=0;bj<4;bj++)
    #pragma unroll
    for (int vi=0;vi<4;vi++) vals[bj][vi] = acc[bj][vi] + barr[vi];

  #pragma unroll
  for (int bj=0;bj<4;bj++){
    int b = (tb<<2)+bj;
    #pragma unroll
    for (int vi=0;vi<4;vi++)
      dst[(size_t)b*strideB + (size_t)(v0+(tv<<2)+vi)*strideV] = vals[bj][vi];
  }

  #pragma unroll
  for (int bj=0;bj<4;bj++){
    float m = vals[bj][0]; int mi = v0+(tv<<2);
    #pragma unroll
    for (int vi=1;vi<4;vi++){
      if (vals[bj][vi] > m){ m = vals[bj][vi]; mi = v0+(tv<<2)+vi; }
    }
    red[(tb<<2)+bj][tv] = mkkey(m, mi);
  }
  __syncthreads();
  if (tid < B){
    ull best = red[tid][0];
    #pragma unroll
    for (int t2=1;t2<16;t2++){ ull k2 = red[tid][t2]; if (k2 > best) best = k2; }
    atomicMax(packedS + tid, best);
  }
}

// ---------------- LDS-tiled transpose: stage bf16 [t][b][v] -> out f32 [b][v][t]
__global__ __launch_bounds__(256) void k_transpose(const unsigned short* __restrict__ stage,
                                                   float* __restrict__ out){
  __shared__ float tile[64][40];           // [v-local][t], padded
  const int b  = blockIdx.x / (V/64);
  const int vt = blockIdx.x % (V/64);
  const int v0 = vt*64;
  const int tid = threadIdx.x;

  for (int idx = tid; idx < T*64; idx += 256){
    int t  = idx >> 6;
    int vl = idx & 63;
    unsigned short u = __builtin_nontemporal_load(stage + (size_t)t*B*V + (size_t)b*V + v0 + vl);
    tile[vl][t] = bf2f(u);
  }
  __syncthreads();

  float* obase = out + ((size_t)b*V + v0)*T;
  for (int idx = tid; idx < (T*64)/4; idx += 256){   // 608 16B stores, contiguous
    int e = idx*4;
    f32x4 o;
    o[0] = tile[(e+0)/T][(e+0)%T];
    o[1] = tile[(e+1)/T][(e+1)%T];
    o[2] = tile[(e+2)/T][(e+2)%T];
    o[3] = tile[(e+3)/T][(e+3)%T];
    __builtin_nontemporal_store(o, (f32x4*)(obase + e));
  }
}

extern "C" void kernel_launch(void* const* d_in, const int* in_sizes, int n_in,
                              void* d_out, int out_size, void* d_ws, size_t ws_size,
                              hipStream_t stream){
  const float* feat      = (const float*)d_in[0];
  const float* W_ih0     = (const float*)d_in[1];
  const float* W_hh0     = (const float*)d_in[2];
  const float* W_ih_rest = (const float*)d_in[3];
  const float* W_hh_rest = (const float*)d_in[4];
  const float* b_ih      = (const float*)d_in[5];
  const float* b_hh      = (const float*)d_in[6];
  const float* embed     = (const float*)d_in[7];
  const float* W_proj    = (const float*)d_in[8];
  const float* b_proj    = (const float*)d_in[9];
  // inputs 10..15 (attention weights) are mathematically dead: enc is l-uniform
  // so softmax over l is uniform and ctx == feat at every step.
  float* out = (float*)d_out;

  char* ws = (char*)d_ws;
  size_t off = 0;
  float* hT = (float*)(ws + off); off += (size_t)2*3*H*B*4;
  float* cT = (float*)(ws + off); off += (size_t)3*H*B*4;
  float* gfeatT = (float*)(ws + off); off += (size_t)4*H*B*4;
  ull* packed = (ull*)(ws + off); off += (size_t)NSTEP*B*8;
  unsigned short* h2bf = (unsigned short*)(ws + off); off += (size_t)B*H*2;
  float* hF32 = (float*)(ws + off); off += (size_t)B*H*4;
  ull* tilemax = (ull*)(ws + off); off += (size_t)B*NTILE*8;
  off = (off + 255) & ~(size_t)255;
  unsigned short* Whi = (unsigned short*)(ws + off); off += (size_t)V*H*2;
  off = (off + 255) & ~(size_t)255;
  unsigned short* stage = (unsigned short*)(ws + off);
  const size_t need = off + (size_t)T*B*V*2;   // ~190 MB total
  const bool fast = (ws_size >= need);

  dim3 bl64x4(64,4);
  k_init_state<<<(3*H*B + 255)/256, 256, 0, stream>>>(feat, hT, cT, packed);
  k_gfeat<<<H, bl64x4, 0, stream>>>(feat, W_ih0, b_ih, b_hh, gfeatT);
  if (fast){
    k_convW<<<(V*H/4)/256, 256, 0, stream>>>(W_proj, Whi);
    k_row0<<<(V+255)/256, 256, 0, stream>>>(embed, W_proj, b_proj, stage, (float*)nullptr, 0);
  } else {
    k_row0<<<(V+255)/256, 256, 0, stream>>>(embed, W_proj, b_proj, (unsigned short*)nullptr, out, 1);
  }

  const size_t LHB = (size_t)H*B;
  for (int s=0; s<NSTEP; s++){
    const int p = s & 1, q = p ^ 1;
    float* hOld = hT + (size_t)p*3*LHB;
    float* hNew = hT + (size_t)q*3*LHB;
    const ull* pk = packed + (size_t)(s>0 ? s-1 : 0)*B;

    k_lstm<<<H, bl64x4, 0, stream>>>(0, s, W_ih0, W_hh0,
        b_ih, b_hh, gfeatT, embed, pk,
        (const float*)nullptr, hOld + 0*LHB, hNew + 0*LHB, cT + 0*LHB,
        (unsigned short*)nullptr, (float*)nullptr);
    k_lstm<<<H, bl64x4, 0, stream>>>(1, s, W_ih_rest, W_hh_rest,
        b_ih + 1*G4, b_hh + 1*G4, (const float*)nullptr, (const float*)nullptr,
        (const ull*)nullptr,
        hNew + 0*LHB, hOld + 1*LHB, hNew + 1*LHB, cT + 1*LHB,
        (unsigned short*)nullptr, (float*)nullptr);
    k_lstm<<<H, bl64x4, 0, stream>>>(2, s, W_ih_rest + (size_t)G4*H, W_hh_rest + (size_t)G4*H,
        b_ih + 2*G4, b_hh + 2*G4, (const float*)nullptr, (const float*)nullptr,
        (const ull*)nullptr,
        hNew + 1*LHB, hOld + 2*LHB, hNew + 2*LHB, cT + 2*LHB,
        fast ? h2bf : (unsigned short*)nullptr,
        fast ? hF32 : (float*)nullptr);

    if (fast){
      unsigned short* plane = stage + (size_t)(s+1)*B*V;
      k_logits_mfma<<<NTILE, 256, 0, stream>>>(Whi, h2bf, b_proj, plane, tilemax);
      k_rescue<<<B, 256, 0, stream>>>(plane, tilemax, hF32, W_proj, b_proj,
                                      packed + (size_t)s*B);
    } else {
      k_logits<<<V/VT, 256, 0, stream>>>(hNew + 2*LHB, W_proj, b_proj,
          out + (s+1), T, V*T, packed + (size_t)s*B);
    }
  }

  if (fast) k_transpose<<<B*(V/64), 256, 0, stream>>>(stage, out);
}